// Round 1
// 245.359 us; speedup vs baseline: 1.2149x; 1.2149x over previous
//
#include <hip/hip_runtime.h>

#define B_ 64
#define T_ 2048
#define LD_ 16
#define HD_ 64
#define K_ 8
#define L_ 16
#define C_ 128
#define S_ 16   // supers (8 chunks each)

// ---------------- workspace layout (floats) ----------------
constexpr int OFF_LE    = 0;                    // T*B*K
constexpr int OFF_ALPHA = 1048576;              // T*B*K  (zT aliases ALPHA+EBAR pre-fwdP3)
constexpr int OFF_EBAR  = 2097152;              // T*B*K
constexpr int OFF_ZT    = OFF_ALPHA;            // T*B*16 = 2097152 floats (dead after emis)
constexpr int OFF_PBUF  = 3145728;              // C*B*64 (P rows; rbuf aliases after fwd scan)
constexpr int OFF_RLOG  = 3670016;              // C*B
constexpr int OFF_AIN   = 3678208;              // C*B*K
constexpr int OFF_SB    = 3743744;              // C*B*K
constexpr int OFF_SBUF  = 3809280;              // S*B*64 = 65536
constexpr int OFF_UBUF  = 3874816;              // S*B*64 = 65536 (frag params live here pre-bwd)
constexpr int OFF_ULOG  = 3940352;              // S*B = 1024
constexpr int OFF_SAIN  = 3941376;              // S*B*K = 8192
constexpr int OFF_BENT  = 3949568;              // S*B*K = 8192
constexpr int OFF_PRM   = 3957760;              // params; total ~15.9 MB

// params region (relative to OFF_PRM), float-indexed
constexpr int P_LINV0 = 0;       // 8*16*16
constexpr int P_LINVT = 2048;    // 8*16*16
constexpr int P_LD0   = 4096;    // 8
constexpr int P_LDT   = 4104;    // 8
constexpr int P_LOGPI = 4112;    // 8
constexpr int P_QEXP  = 4120;    // 64
constexpr int P_QTEXP = 4184;    // 64

// MFMA frag-param block (lives at OFF_UBUF; u32-indexed offsets; uint4 idx = /4)
// FI_W1A1  u32 0      : 8k*4mt*4q*16row uint4  (W1 hi|hi)
// FI_W1A2  u32 8192   : same count              (W1 lo|0)
// FI_LVA1  u32 16384  : 8k*4q*16d uint4         (LinvT hi|hi)
// FI_LVA2  u32 18432  :                          (LinvT lo|0)
// FI_L0A1  u32 20480  :                          (Linv0 hi|hi)
// FI_L0A2  u32 22528  :                          (Linv0 lo|0)
// FI_GAHI  u32 24576  : 8k*2kc*4q*16d uint4     (-Linv W2 hi)
// FI_GALO  u32 28672  :                          (-Linv W2 lo)
constexpr int FI_NC2 = 32768;    // floats: 8k*16d  (-Linv b2)
constexpr int FI_C0I = 32896;    // floats: 8k*16d  (-Linv0 m0)

// output layout (floats)
constexpr int OUT_PAIRED = B_*T_*K_;                       // 1048576
constexpr int OUT_LOGZ   = OUT_PAIRED + B_*(T_-1)*K_*K_;   // 9433088

// ---------------- DPP helpers (aligned groups of 8 lanes) ----------------
template<int CTRL>
__device__ __forceinline__ float dppmov(float x) {
  int xi = __float_as_int(x);
  int r = __builtin_amdgcn_update_dpp(xi, xi, CTRL, 0xF, 0xF, true);
  return __int_as_float(r);
}
// 0xB1=xor1, 0x4E=xor2, 0x141=row_half_mirror=xor7 (within 8)
__device__ __forceinline__ void allg8(float v, float w[8]) {
  w[0] = v;
  w[1] = dppmov<0xB1>(v);
  w[2] = dppmov<0x4E>(v);
  w[3] = dppmov<0x4E>(w[1]);
  w[7] = dppmov<0x141>(v);
  w[6] = dppmov<0xB1>(w[7]);
  w[5] = dppmov<0x4E>(w[7]);
  w[4] = dppmov<0x4E>(w[6]);
}
template<int V> __device__ __forceinline__ float xorg8(float x);
template<> __device__ __forceinline__ float xorg8<0>(float x) { return x; }
template<> __device__ __forceinline__ float xorg8<1>(float x) { return dppmov<0xB1>(x); }
template<> __device__ __forceinline__ float xorg8<2>(float x) { return dppmov<0x4E>(x); }
template<> __device__ __forceinline__ float xorg8<3>(float x) { return dppmov<0x4E>(dppmov<0xB1>(x)); }
template<> __device__ __forceinline__ float xorg8<4>(float x) { return dppmov<0x4E>(dppmov<0xB1>(dppmov<0x141>(x))); }
template<> __device__ __forceinline__ float xorg8<5>(float x) { return dppmov<0x4E>(dppmov<0x141>(x)); }
template<> __device__ __forceinline__ float xorg8<6>(float x) { return dppmov<0xB1>(dppmov<0x141>(x)); }
template<> __device__ __forceinline__ float xorg8<7>(float x) { return dppmov<0x141>(x); }

__device__ __forceinline__ float bfly_sum8(float x) {
  x += dppmov<0xB1>(x); x += dppmov<0x4E>(x); x += dppmov<0x141>(x); return x;
}
__device__ __forceinline__ float bfly_max8(float x) {
  x = fmaxf(x, dppmov<0xB1>(x)); x = fmaxf(x, dppmov<0x4E>(x)); x = fmaxf(x, dppmov<0x141>(x)); return x;
}
__device__ __forceinline__ float rcpnr(float x) {
  float r0 = __builtin_amdgcn_rcpf(x);
  return r0 * __builtin_fmaf(-x, r0, 2.0f);
}
// column-xor layout cl[u]=M[j^u][j] -> row-xor layout rv[v]=M[j][j^v]
__device__ __forceinline__ void col2row(const float cl[8], float rv[8]) {
  rv[0] = cl[0];
  rv[1] = xorg8<1>(cl[1]);
  rv[2] = xorg8<2>(cl[2]);
  rv[3] = xorg8<3>(cl[3]);
  rv[4] = xorg8<4>(cl[4]);
  rv[5] = xorg8<5>(cl[5]);
  rv[6] = xorg8<6>(cl[6]);
  rv[7] = xorg8<7>(cl[7]);
}
// o = A x M, all in row-xor layout: o[v] = sum_u a[u] * M[i^u][i^v]
__device__ __forceinline__ void mmul8(const float a[8], const float m[8], float o[8]) {
  float m8[8][8];
  #pragma unroll
  for (int w = 0; w < 8; w++) allg8(m[w], m8[w]);
  #pragma unroll
  for (int v = 0; v < 8; v++) {
    float acc = 0.f;
    #pragma unroll
    for (int u = 0; u < 8; u++) acc = __builtin_fmaf(a[u], m8[u^v][u], acc);
    o[v] = acc;
  }
}
__device__ __forceinline__ float maxnorm8(float m[8]) {   // returns mx, scales m by 1/mx
  float mx = m[0];
  #pragma unroll
  for (int u = 1; u < 8; u++) mx = fmaxf(mx, m[u]);
  mx = bfly_max8(mx);
  float r = rcpnr(mx);
  #pragma unroll
  for (int u = 0; u < 8; u++) m[u] *= r;
  return mx;
}
__device__ __forceinline__ void load_rows(const float* p, float r[8]) {
  const float4* q = (const float4*)p;
  float4 x0 = q[0], x1 = q[1];
  r[0]=x0.x; r[1]=x0.y; r[2]=x0.z; r[3]=x0.w;
  r[4]=x1.x; r[5]=x1.y; r[6]=x1.z; r[7]=x1.w;
}

// ---------------- MFMA helpers ----------------
typedef __attribute__((ext_vector_type(4))) float f32x4;
typedef __attribute__((ext_vector_type(8))) short bf16x8;

__device__ __forceinline__ unsigned ph(float a, float b) {
  return (__float_as_uint(a) >> 16) | (__float_as_uint(b) & 0xFFFF0000u);
}
__device__ __forceinline__ float hif(float a) {
  return __uint_as_float(__float_as_uint(a) & 0xFFFF0000u);
}
__device__ __forceinline__ bf16x8 u2f(uint4 u) {
  return __builtin_bit_cast(bf16x8, u);
}
// z fragment: slots 0..3 = bf16-hi(z[4q..4q+3]), slots 4..7 = bf16-lo (split precision)
__device__ __forceinline__ bf16x8 mkfrag(float4 v) {
  unsigned ux = __float_as_uint(v.x), uy = __float_as_uint(v.y);
  unsigned uz = __float_as_uint(v.z), uw = __float_as_uint(v.w);
  unsigned h01 = (ux >> 16) | (uy & 0xFFFF0000u);
  unsigned h23 = (uz >> 16) | (uw & 0xFFFF0000u);
  float lx = v.x - __uint_as_float(ux & 0xFFFF0000u);
  float ly = v.y - __uint_as_float(uy & 0xFFFF0000u);
  float lz = v.z - __uint_as_float(uz & 0xFFFF0000u);
  float lw = v.w - __uint_as_float(uw & 0xFFFF0000u);
  unsigned l01 = ph(lx, ly);
  unsigned l23 = ph(lz, lw);
  return u2f(make_uint4(h01, h23, l01, l23));
}
__device__ __forceinline__ f32x4 MF(bf16x8 a, bf16x8 b, f32x4 c) {
  return __builtin_amdgcn_mfma_f32_16x16x32_bf16(a, b, c, 0, 0, 0);
}

// ---------------- kernel 1: Cholesky / softmax params ----------------
__global__ __launch_bounds__(64) void prep_kernel(
    const float* __restrict__ pi, const float* __restrict__ Q,
    const float* __restrict__ init_cov, const float* __restrict__ covs,
    float* __restrict__ prm)
{
  int tid = threadIdx.x;
  int blk = blockIdx.x;
  if (blk < 16) {
    int k = blk & 7;
    const float* C = (blk < 8 ? init_cov : covs) + k*256;
    float* outL  = prm + (blk < 8 ? P_LINV0 : P_LINVT) + k*256;
    float* outld = prm + (blk < 8 ? P_LD0   : P_LDT)   + k;
    __shared__ float S[16][17], L[16][17], X[16][17];
    for (int e = tid; e < 256; e += 64) {
      int r = e >> 4, c = e & 15;
      float s = (r == c) ? 1e-6f : 0.f;
      for (int l = 0; l < 16; l++) s += C[r*16+l] * C[c*16+l];
      S[r][c] = s;
    }
    __syncthreads();
    for (int j = 0; j < 16; j++) {
      if (tid == 0) L[j][j] = sqrtf(S[j][j]);
      __syncthreads();
      if (tid > j && tid < 16) L[tid][j] = S[tid][j] / L[j][j];
      __syncthreads();
      if (tid > j && tid < 16) {
        float ltj = L[tid][j];
        for (int c = j+1; c <= tid; c++) S[tid][c] -= ltj * L[c][j];
      }
      __syncthreads();
    }
    if (tid < 16) {
      int c = tid;
      for (int r = 0; r < 16; r++) {
        float v;
        if (r < c) v = 0.f;
        else {
          v = (r == c) ? 1.f : 0.f;
          for (int s2 = c; s2 < r; s2++) v -= L[r][s2] * X[s2][c];
          v /= L[r][r];
        }
        X[r][c] = v;
      }
    }
    __syncthreads();
    for (int e = tid; e < 256; e += 64) outL[e] = X[e>>4][e&15];
    if (tid == 0) {
      float ld = 0.f;
      for (int j = 0; j < 16; j++) ld += logf(L[j][j]);
      *outld = ld;
    }
  } else {
    if (tid < 8) {
      int row = tid;
      float q[8], mx = -1e30f;
      for (int j = 0; j < 8; j++) { q[j] = Q[row*8+j]; mx = fmaxf(mx, q[j]); }
      float s = 0.f;
      for (int j = 0; j < 8; j++) s += __expf(q[j]-mx);
      float ls = logf(s);
      for (int j = 0; j < 8; j++) {
        float e = __expf(q[j]-mx-ls);
        prm[P_QEXP  + row*8 + j] = e;
        prm[P_QTEXP + j*8 + row] = e;
      }
    } else if (tid == 8) {
      float p[8], mx = -1e30f;
      for (int j = 0; j < 8; j++) { p[j] = pi[j]; mx = fmaxf(mx, p[j]); }
      float s = 0.f;
      for (int j = 0; j < 8; j++) s += __expf(p[j]-mx);
      float ls = logf(s);
      for (int j = 0; j < 8; j++) prm[P_LOGPI+j] = p[j]-mx-ls;
    }
  }
}

// ---------------- kernel 1c: pack MFMA frag params (needs prep output) ------
// A-frag slot convention, shared by every operand pair (k-permutation
// invariant, so any consistent bijection works):
//   GEMM1/GEMM-v (K=16 padded to 32 as [hi|lo]):
//     slot j (lane quadrant q): input-dim l = 4q + (j&3); half = j>>2
//   GEMM2 (K=64, 2 chunks of 32):
//     slot j (quadrant q, chunk kc): hh = 32kc + 16(j>>2) + 4q + (j&3)
//     -> matches GEMM1 C-fragment ownership exactly (no cross-lane moves).
__global__ __launch_bounds__(64) void prep2_kernel(
    const float* __restrict__ W1, const float* __restrict__ W2,
    const float* __restrict__ b2, const float* __restrict__ init_mean,
    const float* __restrict__ prm, float* __restrict__ frag)
{
  int k = blockIdx.x, tid = threadIdx.x;
  __shared__ float Ls[16][16], L0s[16][16], G[16][64];
  for (int e = tid; e < 256; e += 64) {
    Ls[e>>4][e&15]  = prm[P_LINVT + k*256 + e];
    L0s[e>>4][e&15] = prm[P_LINV0 + k*256 + e];
  }
  __syncthreads();
  for (int idx = tid; idx < 1024; idx += 64) {
    int d = idx >> 6, hh = idx & 63;
    float s = 0.f;
    for (int e = 0; e < 16; e++) s += Ls[d][e] * W2[k*1024 + e*64 + hh];
    G[d][hh] = -s;                      // negated: y = Linv zc - G h - Linv b2
  }
  __syncthreads();
  int d = tid & 15, q = tid >> 4;
  uint4* F4 = (uint4*)frag;
  // G frags (GEMM2 A operand)
  for (int kc = 0; kc < 2; kc++) {
    float v[8], lo[8];
    for (int j = 0; j < 8; j++) {
      int hh = 32*kc + 16*(j>>2) + 4*q + (j&3);
      v[j] = G[d][hh];
      lo[j] = v[j] - hif(v[j]);
    }
    F4[6144 + ((k*2+kc)*4+q)*16 + d] =
        make_uint4(ph(v[0],v[1]), ph(v[2],v[3]), ph(v[4],v[5]), ph(v[6],v[7]));
    F4[7168 + ((k*2+kc)*4+q)*16 + d] =
        make_uint4(ph(lo[0],lo[1]), ph(lo[2],lo[3]), ph(lo[4],lo[5]), ph(lo[6],lo[7]));
  }
  // W1 frags (GEMM1 A operand): A1 = [hi|hi], A2 = [lo|0]
  for (int mt = 0; mt < 4; mt++) {
    int hh = 16*mt + d;
    float v[4], lo[4];
    for (int j = 0; j < 4; j++) { v[j] = W1[k*1024 + hh*16 + 4*q + j]; lo[j] = v[j] - hif(v[j]); }
    unsigned x = ph(v[0],v[1]), y = ph(v[2],v[3]);
    F4[((k*4+mt)*4+q)*16 + d]        = make_uint4(x, y, x, y);
    F4[2048 + ((k*4+mt)*4+q)*16 + d] = make_uint4(ph(lo[0],lo[1]), ph(lo[2],lo[3]), 0u, 0u);
  }
  // LinvT / Linv0 frags (GEMM-v A operand)
  {
    float v[4], lo[4];
    for (int j = 0; j < 4; j++) { v[j] = Ls[d][4*q+j]; lo[j] = v[j] - hif(v[j]); }
    unsigned x = ph(v[0],v[1]), y = ph(v[2],v[3]);
    F4[4096 + (k*4+q)*16 + d] = make_uint4(x, y, x, y);
    F4[4608 + (k*4+q)*16 + d] = make_uint4(ph(lo[0],lo[1]), ph(lo[2],lo[3]), 0u, 0u);
    for (int j = 0; j < 4; j++) { v[j] = L0s[d][4*q+j]; lo[j] = v[j] - hif(v[j]); }
    x = ph(v[0],v[1]); y = ph(v[2],v[3]);
    F4[5120 + (k*4+q)*16 + d] = make_uint4(x, y, x, y);
    F4[5632 + (k*4+q)*16 + d] = make_uint4(ph(lo[0],lo[1]), ph(lo[2],lo[3]), 0u, 0u);
  }
  if (q == 0) {
    float s2 = 0.f, s0 = 0.f;
    for (int e = 0; e < 16; e++) {
      s2 += Ls[d][e]  * b2[k*16+e];
      s0 += L0s[d][e] * init_mean[k*16+e];
    }
    frag[FI_NC2 + k*16 + d] = -s2;
    frag[FI_C0I + k*16 + d] = -s0;
  }
}

// ---------------- kernel 1b: z -> time-major zT[t][b][16] --------------------
__global__ __launch_bounds__(256) void ztr_kernel(
    const float* __restrict__ z, float* __restrict__ zt)
{
  int tid = blockIdx.x*256 + threadIdx.x;   // 0..131071
  int t = tid >> 6, b = tid & 63;
  const float4* src = (const float4*)(z + (b*T_ + t)*LD_);
  float4* dst = (float4*)(zt + t*1024 + b*16);
  dst[0] = src[0]; dst[1] = src[1]; dst[2] = src[2]; dst[3] = src[3];
}

// ---------------- kernel 2: emissions via MFMA (split-bf16 ~fp32) ------------
// wave = (k, t-chunk of 16, b-block of 16); lane: c = tr/col (l&15), q = l>>4.
// Transposed orientation: C[d or hh][tr]; all A operands are parameter frags.
//   GEMM1: preact^T = W1 zp^T + b1          (8 MFMA: 4 Mtiles x [hi|hi],[lo|0])
//   GEMM-v: y0 = Linv zc^T - Linv b2       (2 MFMA, C-init = -Linv b2)
//   GEMM2: y -= (Linv W2) h                 (6 MFMA: 2 chunks x 3 precision terms)
//   le = -0.5*sum_d y_d^2 - logdet - 8log(2pi) [+ logpi at t=0]
__global__ __launch_bounds__(256) void emisB_kernel(
    const float* __restrict__ zt, const float* __restrict__ b1,
    const float* __restrict__ frag, const float* __restrict__ prm,
    float* __restrict__ lebuf)
{
  int lane = threadIdx.x & 63;
  int wid = __builtin_amdgcn_readfirstlane(blockIdx.x*4 + (threadIdx.x >> 6));
  int bblk = wid & 3;
  int tch  = (wid >> 2) & 127;
  int k    = wid >> 9;
  int c = lane & 15, q = lane >> 4;
  int b = bblk*16 + c;
  const uint4* F4 = (const uint4*)frag;

  bf16x8 w1a1[4], w1a2[4];
  #pragma unroll
  for (int mt = 0; mt < 4; mt++) {
    w1a1[mt] = u2f(F4[((k*4+mt)*4+q)*16 + c]);
    w1a2[mt] = u2f(F4[2048 + ((k*4+mt)*4+q)*16 + c]);
  }
  bf16x8 lva1 = u2f(F4[4096 + (k*4+q)*16 + c]);
  bf16x8 lva2 = u2f(F4[4608 + (k*4+q)*16 + c]);
  bf16x8 gahi[2], galo[2];
  #pragma unroll
  for (int kc = 0; kc < 2; kc++) {
    gahi[kc] = u2f(F4[6144 + ((k*2+kc)*4+q)*16 + c]);
    galo[kc] = u2f(F4[7168 + ((k*2+kc)*4+q)*16 + c]);
  }
  float b1iv[16];
  #pragma unroll
  for (int i = 0; i < 16; i++)           // i = mt*4+r ; hh = 16mt + 4q + r
    b1iv[i] = b1[k*64 + (i>>2)*16 + 4*q + (i&3)];
  float nc2[4];
  #pragma unroll
  for (int r = 0; r < 4; r++) nc2[r] = frag[FI_NC2 + k*16 + 4*q + r];
  float lconst = -prm[P_LDT + k] - 14.70301653f;

  int t0 = tch*16;
  bf16x8 zp;
  int ttstart;
  if (tch == 0) {
    // t = 0: initial-state emission (Linv0, init_mean, +logpi)
    float4 zv0 = *(const float4*)(zt + b*16 + 4*q);
    bf16x8 zc0 = mkfrag(zv0);
    bf16x8 l0a1 = u2f(F4[5120 + (k*4+q)*16 + c]);
    bf16x8 l0a2 = u2f(F4[5632 + (k*4+q)*16 + c]);
    f32x4 acc;
    acc[0] = frag[FI_C0I + k*16 + 4*q + 0];
    acc[1] = frag[FI_C0I + k*16 + 4*q + 1];
    acc[2] = frag[FI_C0I + k*16 + 4*q + 2];
    acc[3] = frag[FI_C0I + k*16 + 4*q + 3];
    acc = MF(l0a1, zc0, acc);
    acc = MF(l0a2, zc0, acc);
    float m2 = (acc[0]*acc[0] + acc[1]*acc[1]) + (acc[2]*acc[2] + acc[3]*acc[3]);
    m2 += __shfl_xor(m2, 16);
    m2 += __shfl_xor(m2, 32);
    float le = -0.5f*m2 - prm[P_LD0+k] - 14.70301653f + prm[P_LOGPI+k];
    if (q == 0) lebuf[k*64 + b] = le;
    zp = zc0;
    ttstart = 1;
  } else {
    float4 zvp = *(const float4*)(zt + (t0-1)*1024 + b*16 + 4*q);
    zp = mkfrag(zvp);
    ttstart = 0;
  }

  float4 zv = *(const float4*)(zt + (t0+ttstart)*1024 + b*16 + 4*q);
  #pragma unroll 1
  for (int tt = ttstart; tt < 16; tt++) {
    int t = t0 + tt;
    float4 zvn;
    if (tt < 15) zvn = *(const float4*)(zt + (t+1)*1024 + b*16 + 4*q);
    bf16x8 zc = mkfrag(zv);
    // GEMM1: preact^T = W1 zp^T + b1
    f32x4 a1[4];
    #pragma unroll
    for (int mt = 0; mt < 4; mt++) {
      f32x4 ai;
      ai[0] = b1iv[mt*4+0]; ai[1] = b1iv[mt*4+1];
      ai[2] = b1iv[mt*4+2]; ai[3] = b1iv[mt*4+3];
      ai = MF(w1a1[mt], zp, ai);
      a1[mt] = MF(w1a2[mt], zp, ai);
    }
    // softplus
    float hv[16];
    #pragma unroll
    for (int i = 0; i < 16; i++) {
      float a = a1[i>>2][i&3];
      hv[i] = fmaxf(a, 0.f) + __logf(1.f + __expf(-fabsf(a)));
    }
    // h fragments: slot j of chunk kc = hv[8kc + j] (exactly lane-local)
    bf16x8 hhi[2], hlo[2];
    #pragma unroll
    for (int kc = 0; kc < 2; kc++) {
      const float* hp = hv + 8*kc;
      hhi[kc] = u2f(make_uint4(ph(hp[0],hp[1]), ph(hp[2],hp[3]),
                               ph(hp[4],hp[5]), ph(hp[6],hp[7])));
      float l0 = hp[0]-hif(hp[0]), l1 = hp[1]-hif(hp[1]);
      float l2 = hp[2]-hif(hp[2]), l3 = hp[3]-hif(hp[3]);
      float l4 = hp[4]-hif(hp[4]), l5 = hp[5]-hif(hp[5]);
      float l6 = hp[6]-hif(hp[6]), l7 = hp[7]-hif(hp[7]);
      hlo[kc] = u2f(make_uint4(ph(l0,l1), ph(l2,l3), ph(l4,l5), ph(l6,l7)));
    }
    // GEMM-v + GEMM2: y = Linv zc - Linv b2 - G h
    f32x4 acc;
    acc[0] = nc2[0]; acc[1] = nc2[1]; acc[2] = nc2[2]; acc[3] = nc2[3];
    acc = MF(lva1, zc, acc);
    acc = MF(lva2, zc, acc);
    #pragma unroll
    for (int kc = 0; kc < 2; kc++) {
      acc = MF(gahi[kc], hhi[kc], acc);
      acc = MF(galo[kc], hhi[kc], acc);
      acc = MF(gahi[kc], hlo[kc], acc);
    }
    float m2 = (acc[0]*acc[0] + acc[1]*acc[1]) + (acc[2]*acc[2] + acc[3]*acc[3]);
    m2 += __shfl_xor(m2, 16);
    m2 += __shfl_xor(m2, 32);
    float le = -0.5f*m2 + lconst;
    if (q == 0) lebuf[t*512 + k*64 + b] = le;
    zp = zc;
    zv = zvn;
  }
}

// ---------------- fwd P1: per-(b,chunk) operator products -> ROW layout ------
__global__ __launch_bounds__(256) void fwdP1_kernel(
    const float* __restrict__ lebuf, const float* __restrict__ prm,
    float* __restrict__ pbuf)
{
  int g = (blockIdx.x*256 + threadIdx.x) >> 3;   // 0..8191
  int j = threadIdx.x & 7;
  int b = g & 63, c = g >> 6;                    // c 0..127
  float qtv[64];
  #pragma unroll
  for (int u = 0; u < 8; u++)
    #pragma unroll
    for (int v = 0; v < 8; v++)
      qtv[u*8+v] = prm[P_QTEXP + (j^u)*8 + (j^v)];
  float lev[16];
  #pragma unroll
  for (int u = 0; u < 16; u++) lev[u] = lebuf[(c*L_+u)*512 + j*64 + b];
  float pl[8];
  int ustart;
  if (c == 0) {
    float m = bfly_max8(lev[0]);
    float e = __expf(lev[0]-m);
    allg8(e, pl);                // P[:,j] = ehat_0 (all columns equal)
    ustart = 1;
  } else {
    #pragma unroll
    for (int u = 0; u < 8; u++) pl[u] = (u == 0) ? 1.f : 0.f;
    ustart = 0;
  }
  for (int s = ustart; s < 16; s++) {
    float m = bfly_max8(lev[s]);
    float e = __expf(lev[s]-m);
    float e8[8]; allg8(e, e8);
    float np[8];
    #pragma unroll
    for (int u = 0; u < 8; u++) {
      float acc = 0.f;
      #pragma unroll
      for (int v = 0; v < 8; v++) acc = __builtin_fmaf(qtv[u*8+v], pl[v], acc);
      np[u] = e8[u] * acc;
    }
    float mx = np[0];
    #pragma unroll
    for (int u = 1; u < 8; u++) mx = fmaxf(mx, np[u]);
    mx = bfly_max8(mx);
    float r = rcpnr(mx);
    #pragma unroll
    for (int u = 0; u < 8; u++) pl[u] = np[u] * r;
  }
  float rv[8]; col2row(pl, rv);
  float4* dst = (float4*)(pbuf + g*64 + j*8);
  dst[0] = make_float4(rv[0], rv[1], rv[2], rv[3]);
  dst[1] = make_float4(rv[4], rv[5], rv[6], rv[7]);
}

// ---------------- fwd P2a: super-chunk products S_s = P_{8s+7}...P_{8s} ------
__global__ __launch_bounds__(256) void fwdP2a_kernel(
    const float* __restrict__ pbuf, float* __restrict__ sbuf)
{
  int g = (blockIdx.x*256 + threadIdx.x) >> 3;   // 0..1023
  int i = threadIdx.x & 7;
  int b = g & 63, s = g >> 6;                    // s 0..15
  float m[8];
  load_rows(pbuf + ((8*s)*64 + b)*64 + i*8, m);
  for (int c = 8*s+1; c <= 8*s+7; c++) {
    float a[8];
    load_rows(pbuf + (c*64 + b)*64 + i*8, a);
    float nm[8];
    mmul8(a, m, nm);
    maxnorm8(nm);
    #pragma unroll
    for (int v = 0; v < 8; v++) m[v] = nm[v];
  }
  float4* dst = (float4*)(sbuf + (s*64 + b)*64 + i*8);
  dst[0] = make_float4(m[0], m[1], m[2], m[3]);
  dst[1] = make_float4(m[4], m[5], m[6], m[7]);
}

// ---------------- fwd P2b: serial over 16 supers -> sain ---------------------
__global__ __launch_bounds__(512) void fwdP2b_kernel(
    const float* __restrict__ sbuf, float* __restrict__ sain)
{
  int lane = threadIdx.x;
  int b = lane >> 3, i = lane & 7;
  const float4* base = (const float4*)sbuf;
  float4 c0 = base[(0*64+b)*16 + i*2], c1 = base[(0*64+b)*16 + i*2 + 1];
  float a = 0.125f;
  for (int s = 0; s < 16; s++) {
    int s2 = (s < 15) ? s+1 : 15;
    float4 n0 = base[(s2*64+b)*16 + i*2], n1 = base[(s2*64+b)*16 + i*2 + 1];
    float aw[8]; allg8(a, aw);
    float sm = ((c0.x*aw[0] + c0.y*aw[1]) + (c0.z*aw[2] + c0.w*aw[3]))
             + ((c1.x*aw[4] + c1.y*aw[5]) + (c1.z*aw[6] + c1.w*aw[7]));
    float tot = bfly_sum8(sm);
    float an = sm * rcpnr(tot);
    if (s < 15) { a = an; sain[(s+1)*512 + b*8 + i] = a; }
    c0 = n0; c1 = n1;
  }
}

// ---------------- fwd P2c: per-super walk -> ain for every chunk -------------
__global__ __launch_bounds__(256) void fwdP2c_kernel(
    const float* __restrict__ pbuf, const float* __restrict__ sain,
    float* __restrict__ ain)
{
  int g = (blockIdx.x*256 + threadIdx.x) >> 3;   // 0..1023
  int i = threadIdx.x & 7;
  int b = g & 63, s = g >> 6;
  float a = (s == 0) ? 0.125f : sain[s*512 + b*8 + i];
  ain[(8*s)*512 + b*8 + i] = a;
  for (int u = 0; u < 7; u++) {
    int c = 8*s + u;
    float r[8];
    load_rows(pbuf + (c*64 + b)*64 + i*8, r);
    float aw[8]; allg8(a, aw);
    float sm = ((r[0]*aw[0] + r[1]*aw[1]) + (r[2]*aw[2] + r[3]*aw[3]))
             + ((r[4]*aw[4] + r[5]*aw[5]) + (r[6]*aw[6] + r[7]*aw[7]));
    float tot = bfly_sum8(sm);
    a = sm * rcpnr(tot);
    ain[(c+1)*512 + b*8 + i] = a;
  }
}

// ---------------- fwd P3 (+ fused bwd chunk products -> ROW layout) ----------
__global__ __launch_bounds__(256) void fwdP3_kernel(
    const float* __restrict__ lebuf, const float* __restrict__ prm,
    const float* __restrict__ ain, float* __restrict__ alpha,
    float* __restrict__ ebar, float* __restrict__ rbuf,
    float* __restrict__ rlog, float* __restrict__ out)
{
  int g = (blockIdx.x*256 + threadIdx.x) >> 3;
  int i = threadIdx.x & 7;
  int b = g & 63, c = g >> 6;
  int off = b*8 + i;
  float q[8];
  #pragma unroll
  for (int u = 0; u < 8; u++) q[u] = prm[P_QTEXP + i*8 + (i^u)];
  float lev[16];
  #pragma unroll
  for (int u = 0; u < 16; u++) lev[u] = lebuf[(c*L_+u)*512 + i*64 + b];
  float* logZ = out + OUT_LOGZ + b*T_;
  float eb_loc[16];
  float a;
  int ustart;
  if (c == 0) {
    float m0 = bfly_max8(lev[0]);
    float e0 = __expf(lev[0]-m0);
    float ct = bfly_sum8(e0);
    float r = rcpnr(ct);
    a = e0 * r;
    alpha[off] = a;
    eb_loc[0] = a;
    ebar[off] = a;
    if (i == 0) logZ[0] = m0 + __logf(ct);
    ustart = 1;
  } else {
    a = ain[c*512 + off];
    ustart = 0;
  }
  for (int u = ustart; u < 16; u++) {
    int t = c*L_ + u;
    float m = bfly_max8(lev[u]);
    float e = __expf(lev[u]-m);
    float w[8]; allg8(a, w);
    float dot = ((q[0]*w[0]+q[1]*w[1]) + (q[2]*w[2]+q[3]*w[3]))
              + ((q[4]*w[4]+q[5]*w[5]) + (q[6]*w[6]+q[7]*w[7]));
    float p = e * dot;
    float ct = bfly_sum8(p);
    float r = rcpnr(ct);
    a = p * r;
    alpha[t*512 + off] = a;
    float eb = e * r;
    eb_loc[u] = eb;
    ebar[t*512 + off] = eb;
    if (i == 0) logZ[t] = m + __logf(ct);
  }
  // fused backward chunk product: R_c = Q E_{cL+1} ... Q E_{cL+15}
  float qv[64];
  #pragma unroll
  for (int u = 0; u < 8; u++)
    #pragma unroll
    for (int v = 0; v < 8; v++)
      qv[u*8+v] = prm[P_QEXP + (i^u)*8 + (i^v)];
  float rl[8];
  #pragma unroll
  for (int u = 0; u < 8; u++) rl[u] = (u == 0) ? 1.f : 0.f;
  float lsc = 0.f;
  #pragma unroll
  for (int s = 15; s >= 1; s--) {
    float e8[8]; allg8(eb_loc[s], e8);
    float nr[8];
    #pragma unroll
    for (int u = 0; u < 8; u++) {
      float acc = 0.f;
      #pragma unroll
      for (int v = 0; v < 8; v++) acc = __builtin_fmaf(qv[u*8+v], e8[v]*rl[v], acc);
      nr[u] = acc;
    }
    float mx = nr[0];
    #pragma unroll
    for (int u = 1; u < 8; u++) mx = fmaxf(mx, nr[u]);
    mx = bfly_max8(mx);
    float r = rcpnr(mx);
    #pragma unroll
    for (int u = 0; u < 8; u++) rl[u] = nr[u] * r;
    lsc += __logf(mx);
  }
  float rv[8]; col2row(rl, rv);
  float4* dst = (float4*)(rbuf + g*64 + i*8);
  dst[0] = make_float4(rv[0], rv[1], rv[2], rv[3]);
  dst[1] = make_float4(rv[4], rv[5], rv[6], rv[7]);
  if (i == 0) rlog[g] = lsc;
}

// ---------------- bwd P2a: super products U_s = G_{8s}...G_{8s+7} ------------
// G_c = Q diag(ebar_{c*16}) R_c ; stored max-normalized with log ulog
__global__ __launch_bounds__(256) void bwdP2a_kernel(
    const float* __restrict__ rbuf, const float* __restrict__ rlog,
    const float* __restrict__ ebar, const float* __restrict__ prm,
    float* __restrict__ ubuf, float* __restrict__ ulog)
{
  int g = (blockIdx.x*256 + threadIdx.x) >> 3;   // 0..1023
  int i = threadIdx.x & 7;
  int b = g & 63, s = g >> 6;
  float qr[8];
  #pragma unroll
  for (int u = 0; u < 8; u++) qr[u] = prm[P_QEXP + i*8 + (i^u)];
  float m[8], lsum;
  {
    int c = 8*s + 7;
    float r[8];
    load_rows(rbuf + (c*64 + b)*64 + i*8, r);
    float e = ebar[(c*L_)*512 + b*8 + i];
    float d[8];
    #pragma unroll
    for (int v = 0; v < 8; v++) d[v] = e * r[v];
    mmul8(qr, d, m);
    lsum = rlog[c*64 + b] + __logf(maxnorm8(m));
  }
  for (int c = 8*s + 6; c >= 8*s; c--) {
    float r[8];
    load_rows(rbuf + (c*64 + b)*64 + i*8, r);
    float e = ebar[(c*L_)*512 + b*8 + i];
    float t[8];
    mmul8(r, m, t);                      // T = R_c x M
    #pragma unroll
    for (int v = 0; v < 8; v++) t[v] *= e;   // diag(e) T
    float nm[8];
    mmul8(qr, t, nm);                    // M' = Q x (diag(e) T)
    lsum += rlog[c*64 + b] + __logf(maxnorm8(nm));
    #pragma unroll
    for (int v = 0; v < 8; v++) m[v] = nm[v];
  }
  float4* dst = (float4*)(ubuf + (s*64 + b)*64 + i*8);
  dst[0] = make_float4(m[0], m[1], m[2], m[3]);
  dst[1] = make_float4(m[4], m[5], m[6], m[7]);
  if (i == 0) ulog[s*64 + b] = lsum;
}

// ---------------- bwd P2b: serial over supers -> bent (beta at super tops) ---
__global__ __launch_bounds__(512) void bwdP2b_kernel(
    const float* __restrict__ ubuf, const float* __restrict__ ulog,
    float* __restrict__ bent)
{
  int lane = threadIdx.x;
  int b = lane >> 3, i = lane & 7;
  bent[15*512 + b*8 + i] = 1.f;
  const float4* base = (const float4*)ubuf;
  float sh = 1.f, sig = 0.f;              // true beta_top = sh * exp(sig)
  float4 c0 = base[(15*64+b)*16 + i*2], c1 = base[(15*64+b)*16 + i*2 + 1];
  float cu = ulog[15*64 + b];
  for (int s = 15; s >= 1; s--) {
    int s2 = (s > 1) ? s-1 : 1;
    float4 n0 = base[(s2*64+b)*16 + i*2], n1 = base[(s2*64+b)*16 + i*2 + 1];
    float nu = ulog[s2*64 + b];
    float sw[8]; allg8(sh, sw);
    float y = ((c0.x*sw[0] + c0.y*sw[1]) + (c0.z*sw[2] + c0.w*sw[3]))
            + ((c1.x*sw[4] + c1.y*sw[5]) + (c1.z*sw[6] + c1.w*sw[7]));
    float mx = bfly_max8(y);
    sh = y * rcpnr(mx);
    sig += cu + __logf(mx);
    bent[(s-1)*512 + b*8 + i] = sh * __expf(sig);
    c0 = n0; c1 = n1; cu = nu;
  }
}

// ---------------- bwd P2c: per-super walk -> sb (beta at chunk bottoms) ------
__global__ __launch_bounds__(256) void bwdP2c_kernel(
    const float* __restrict__ rbuf, const float* __restrict__ rlog,
    const float* __restrict__ ebar, const float* __restrict__ prm,
    const float* __restrict__ bent, float* __restrict__ sb)
{
  int g = (blockIdx.x*256 + threadIdx.x) >> 3;   // 0..1023
  int i = threadIdx.x & 7;
  int b = g & 63, s = g >> 6;
  float qr[8];
  #pragma unroll
  for (int u = 0; u < 8; u++) qr[u] = prm[P_QEXP + i*8 + (i^u)];
  float bt = bent[s*512 + b*8 + i];       // beta at top of super s (actual)
  for (int c = 8*s + 7; c >= 8*s; c--) {
    float r[8];
    load_rows(rbuf + (c*64 + b)*64 + i*8, r);
    float e = ebar[(c*L_)*512 + b*8 + i];
    float rl = rlog[c*64 + b];
    float btw[8]; allg8(bt, btw);
    float y = ((r[0]*btw[0] + r[1]*btw[1]) + (r[2]*btw[2] + r[3]*btw[3]))
            + ((r[4]*btw[4] + r[5]*btw[5]) + (r[6]*btw[6] + r[7]*btw[7]));
    y *= __expf(rl);                      // beta at t = c*16 (actual)
    sb[c*512 + b*8 + i] = y;
    float w[8]; allg8(e*y, w);
    float nb = 0.f;
    #pragma unroll
    for (int v = 0; v < 8; v++) nb = __builtin_fmaf(qr[v], w[v], nb);
    bt = nb;                              // beta at t = c*16-1
  }
}

// ---------------- bwd P3 fused with gamma/paired emission --------------------
__global__ __launch_bounds__(256) void bwdP3_kernel(
    const float* __restrict__ alpha, const float* __restrict__ ebar,
    const float* __restrict__ sb, const float* __restrict__ prm,
    float* __restrict__ out)
{
  int g = (blockIdx.x*256 + threadIdx.x) >> 3;
  int i = threadIdx.x & 7;
  int b = g & 63, c = g >> 6;
  int off = b*8 + i;
  float q[8];
  #pragma unroll
  for (int u = 0; u < 8; u++) q[u] = prm[P_QEXP + i*8 + (i^u)];
  float av[16], ev[16];
  #pragma unroll
  for (int u = 0; u < 16; u++) av[u] = alpha[(c*L_+u)*512 + off];
  #pragma unroll
  for (int u = 1; u < 16; u++) ev[u] = ebar[(c*L_+u)*512 + off];
  float* po = out + OUT_PAIRED + b*((T_-1)*64);
  float* go = out + b*(T_*K_);
  float bb;
  if (c == 127) {
    bb = 1.f;
    go[2047*8 + i] = av[15];             // gamma at t=2047 (beta=1)
  } else {
    float ev16 = ebar[((c+1)*L_)*512 + off];
    float sbv  = sb[(c+1)*512 + off];
    float w[8]; allg8(ev16*sbv, w);
    bb = ((q[0]*w[0]+q[1]*w[1]) + (q[2]*w[2]+q[3]*w[3]))
       + ((q[4]*w[4]+q[5]*w[5]) + (q[6]*w[6]+q[7]*w[7]));
    int t = c*L_ + 15;
    #pragma unroll
    for (int u2 = 0; u2 < 8; u2++)
      po[t*64 + i*8 + (i^u2)] = av[15] * q[u2] * w[u2];
    go[t*8 + i] = av[15] * bb;
  }
  #pragma unroll
  for (int u = 15; u >= 1; u--) {
    float w[8]; allg8(ev[u]*bb, w);
    float nb = ((q[0]*w[0]+q[1]*w[1]) + (q[2]*w[2]+q[3]*w[3]))
             + ((q[4]*w[4]+q[5]*w[5]) + (q[6]*w[6]+q[7]*w[7]));
    int t = c*L_ + u - 1;
    #pragma unroll
    for (int u2 = 0; u2 < 8; u2++)
      po[t*64 + i*8 + (i^u2)] = av[u-1] * q[u2] * w[u2];
    go[t*8 + i] = av[u-1] * nb;
    bb = nb;
  }
}

extern "C" void kernel_launch(void* const* d_in, const int* in_sizes, int n_in,
                              void* d_out, int out_size, void* d_ws, size_t ws_size,
                              hipStream_t stream) {
  const float* z         = (const float*)d_in[0];
  const float* pi        = (const float*)d_in[1];
  const float* Q         = (const float*)d_in[2];
  const float* init_mean = (const float*)d_in[3];
  const float* init_cov  = (const float*)d_in[4];
  const float* covs      = (const float*)d_in[5];
  const float* W1        = (const float*)d_in[6];
  const float* b1        = (const float*)d_in[7];
  const float* W2        = (const float*)d_in[8];
  const float* b2        = (const float*)d_in[9];
  float* out = (float*)d_out;
  float* ws  = (float*)d_ws;

  prep_kernel<<<17, 64, 0, stream>>>(pi, Q, init_cov, covs, ws + OFF_PRM);
  prep2_kernel<<<8, 64, 0, stream>>>(W1, W2, b2, init_mean, ws + OFF_PRM,
                                     ws + OFF_UBUF);
  ztr_kernel<<<512, 256, 0, stream>>>(z, ws + OFF_ZT);
  emisB_kernel<<<1024, 256, 0, stream>>>(ws + OFF_ZT, b1, ws + OFF_UBUF,
                                         ws + OFF_PRM, ws + OFF_LE);
  fwdP1_kernel<<<256, 256, 0, stream>>>(ws + OFF_LE, ws + OFF_PRM, ws + OFF_PBUF);
  fwdP2a_kernel<<<32, 256, 0, stream>>>(ws + OFF_PBUF, ws + OFF_SBUF);
  fwdP2b_kernel<<<1, 512, 0, stream>>>(ws + OFF_SBUF, ws + OFF_SAIN);
  fwdP2c_kernel<<<32, 256, 0, stream>>>(ws + OFF_PBUF, ws + OFF_SAIN, ws + OFF_AIN);
  fwdP3_kernel<<<256, 256, 0, stream>>>(ws + OFF_LE, ws + OFF_PRM, ws + OFF_AIN,
                                        ws + OFF_ALPHA, ws + OFF_EBAR,
                                        ws + OFF_PBUF, ws + OFF_RLOG, out);
  bwdP2a_kernel<<<32, 256, 0, stream>>>(ws + OFF_PBUF, ws + OFF_RLOG,
                                        ws + OFF_EBAR, ws + OFF_PRM,
                                        ws + OFF_UBUF, ws + OFF_ULOG);
  bwdP2b_kernel<<<1, 512, 0, stream>>>(ws + OFF_UBUF, ws + OFF_ULOG, ws + OFF_BENT);
  bwdP2c_kernel<<<32, 256, 0, stream>>>(ws + OFF_PBUF, ws + OFF_RLOG,
                                        ws + OFF_EBAR, ws + OFF_PRM,
                                        ws + OFF_BENT, ws + OFF_SB);
  bwdP3_kernel<<<256, 256, 0, stream>>>(ws + OFF_ALPHA, ws + OFF_EBAR,
                                        ws + OFF_SB, ws + OFF_PRM, out);
}

// Round 3
// 230.772 us; speedup vs baseline: 1.2917x; 1.0632x over previous
//
#include <hip/hip_runtime.h>

#define B_ 64
#define T_ 2048
#define LD_ 16
#define HD_ 64
#define K_ 8
#define L_ 16
#define C_ 128
#define S_ 16   // supers (8 chunks each)

// ---------------- workspace layout (floats) ----------------
constexpr int OFF_LE    = 0;                    // T*B*K
constexpr int OFF_ALPHA = 1048576;              // T*B*K  (zT aliases ALPHA+EBAR pre-fwdB)
constexpr int OFF_EBAR  = 2097152;              // T*B*K
constexpr int OFF_ZT    = OFF_ALPHA;            // T*B*16 = 2097152 floats (dead after emis)
constexpr int OFF_PBUF  = 3145728;              // C*B*64 (P rows; R rows alias after fwdB)
constexpr int OFF_RLOG  = 3670016;              // C*B
constexpr int OFF_SBUF  = 3809280;              // S*B*64 = 65536
constexpr int OFF_UBUF  = 3874816;              // S*B*64 = 65536 (frag params live here pre-fwdB)
constexpr int OFF_ULOG  = 3940352;              // S*B = 1024
constexpr int OFF_SAIN  = 3941376;              // S*B*K = 8192
constexpr int OFF_BENT  = 3949568;              // S*B*K = 8192
constexpr int OFF_PRM   = 3957760;              // params; total ~15.9 MB

// params region (relative to OFF_PRM), float-indexed
constexpr int P_LINV0 = 0;       // 8*16*16
constexpr int P_LINVT = 2048;    // 8*16*16
constexpr int P_LD0   = 4096;    // 8
constexpr int P_LDT   = 4104;    // 8
constexpr int P_LOGPI = 4112;    // 8
constexpr int P_QEXP  = 4120;    // 64
constexpr int P_QTEXP = 4184;    // 64

// MFMA frag-param block (lives at OFF_UBUF; uint4 idx = u32/4)
constexpr int FI_NC2 = 32768;    // floats: 8k*16d  (-Linv b2)
constexpr int FI_C0I = 32896;    // floats: 8k*16d  (-Linv0 m0)

// output layout (floats)
constexpr int OUT_PAIRED = B_*T_*K_;                       // 1048576
constexpr int OUT_LOGZ   = OUT_PAIRED + B_*(T_-1)*K_*K_;   // 9433088

// ---------------- DPP helpers (aligned groups of 8 lanes) ----------------
template<int CTRL>
__device__ __forceinline__ float dppmov(float x) {
  int xi = __float_as_int(x);
  int r = __builtin_amdgcn_update_dpp(xi, xi, CTRL, 0xF, 0xF, true);
  return __int_as_float(r);
}
// 0xB1=xor1, 0x4E=xor2, 0x141=row_half_mirror=xor7 (within 8)
__device__ __forceinline__ void allg8(float v, float w[8]) {
  w[0] = v;
  w[1] = dppmov<0xB1>(v);
  w[2] = dppmov<0x4E>(v);
  w[3] = dppmov<0x4E>(w[1]);
  w[7] = dppmov<0x141>(v);
  w[6] = dppmov<0xB1>(w[7]);
  w[5] = dppmov<0x4E>(w[7]);
  w[4] = dppmov<0x4E>(w[6]);
}
template<int V> __device__ __forceinline__ float xorg8(float x);
template<> __device__ __forceinline__ float xorg8<0>(float x) { return x; }
template<> __device__ __forceinline__ float xorg8<1>(float x) { return dppmov<0xB1>(x); }
template<> __device__ __forceinline__ float xorg8<2>(float x) { return dppmov<0x4E>(x); }
template<> __device__ __forceinline__ float xorg8<3>(float x) { return dppmov<0x4E>(dppmov<0xB1>(x)); }
template<> __device__ __forceinline__ float xorg8<4>(float x) { return dppmov<0x4E>(dppmov<0xB1>(dppmov<0x141>(x))); }
template<> __device__ __forceinline__ float xorg8<5>(float x) { return dppmov<0x4E>(dppmov<0x141>(x)); }
template<> __device__ __forceinline__ float xorg8<6>(float x) { return dppmov<0xB1>(dppmov<0x141>(x)); }
template<> __device__ __forceinline__ float xorg8<7>(float x) { return dppmov<0x141>(x); }

__device__ __forceinline__ float bfly_sum8(float x) {
  x += dppmov<0xB1>(x); x += dppmov<0x4E>(x); x += dppmov<0x141>(x); return x;
}
__device__ __forceinline__ float bfly_max8(float x) {
  x = fmaxf(x, dppmov<0xB1>(x)); x = fmaxf(x, dppmov<0x4E>(x)); x = fmaxf(x, dppmov<0x141>(x)); return x;
}
__device__ __forceinline__ float rcpnr(float x) {
  float r0 = __builtin_amdgcn_rcpf(x);
  return r0 * __builtin_fmaf(-x, r0, 2.0f);
}
// absolute gather within aligned 8-lane group: w[v] = value at lane (base8+v)
// ds_swizzle BitMode: src = ((lane & 0x18) | v)  -> offset = (v<<5) | 0x18
__device__ __forceinline__ void absg8(float v, float w[8]) {
  int x = __float_as_int(v);
  w[0] = __int_as_float(__builtin_amdgcn_ds_swizzle(x, 0x18));
  w[1] = __int_as_float(__builtin_amdgcn_ds_swizzle(x, 0x38));
  w[2] = __int_as_float(__builtin_amdgcn_ds_swizzle(x, 0x58));
  w[3] = __int_as_float(__builtin_amdgcn_ds_swizzle(x, 0x78));
  w[4] = __int_as_float(__builtin_amdgcn_ds_swizzle(x, 0x98));
  w[5] = __int_as_float(__builtin_amdgcn_ds_swizzle(x, 0xB8));
  w[6] = __int_as_float(__builtin_amdgcn_ds_swizzle(x, 0xD8));
  w[7] = __int_as_float(__builtin_amdgcn_ds_swizzle(x, 0xF8));
}
// column-xor layout cl[u]=M[j^u][j] -> row-xor layout rv[v]=M[j][j^v]
__device__ __forceinline__ void col2row(const float cl[8], float rv[8]) {
  rv[0] = cl[0];
  rv[1] = xorg8<1>(cl[1]);
  rv[2] = xorg8<2>(cl[2]);
  rv[3] = xorg8<3>(cl[3]);
  rv[4] = xorg8<4>(cl[4]);
  rv[5] = xorg8<5>(cl[5]);
  rv[6] = xorg8<6>(cl[6]);
  rv[7] = xorg8<7>(cl[7]);
}
// o = A x M, all in row-xor layout: o[v] = sum_u a[u] * M[i^u][i^v]
__device__ __forceinline__ void mmul8(const float a[8], const float m[8], float o[8]) {
  float m8[8][8];
  #pragma unroll
  for (int w = 0; w < 8; w++) allg8(m[w], m8[w]);
  #pragma unroll
  for (int v = 0; v < 8; v++) {
    float acc = 0.f;
    #pragma unroll
    for (int u = 0; u < 8; u++) acc = __builtin_fmaf(a[u], m8[u^v][u], acc);
    o[v] = acc;
  }
}
__device__ __forceinline__ float maxnorm8(float m[8]) {   // returns mx, scales m by 1/mx
  float mx = m[0];
  #pragma unroll
  for (int u = 1; u < 8; u++) mx = fmaxf(mx, m[u]);
  mx = bfly_max8(mx);
  float r = rcpnr(mx);
  #pragma unroll
  for (int u = 0; u < 8; u++) m[u] *= r;
  return mx;
}
__device__ __forceinline__ void load_rows(const float* p, float r[8]) {
  const float4* q = (const float4*)p;
  float4 x0 = q[0], x1 = q[1];
  r[0]=x0.x; r[1]=x0.y; r[2]=x0.z; r[3]=x0.w;
  r[4]=x1.x; r[5]=x1.y; r[6]=x1.z; r[7]=x1.w;
}
__device__ __forceinline__ float dotw8(const float r[8], const float w[8]) {
  return ((r[0]*w[0]+r[1]*w[1]) + (r[2]*w[2]+r[3]*w[3]))
       + ((r[4]*w[4]+r[5]*w[5]) + (r[6]*w[6]+r[7]*w[7]));
}

// ---------------- MFMA helpers ----------------
typedef __attribute__((ext_vector_type(4))) float f32x4;
typedef __attribute__((ext_vector_type(8))) short bf16x8;

__device__ __forceinline__ unsigned ph(float a, float b) {
  return (__float_as_uint(a) >> 16) | (__float_as_uint(b) & 0xFFFF0000u);
}
__device__ __forceinline__ float hif(float a) {
  return __uint_as_float(__float_as_uint(a) & 0xFFFF0000u);
}
__device__ __forceinline__ bf16x8 u2f(uint4 u) {
  return __builtin_bit_cast(bf16x8, u);
}
__device__ __forceinline__ bf16x8 mkfrag(float4 v) {
  unsigned ux = __float_as_uint(v.x), uy = __float_as_uint(v.y);
  unsigned uz = __float_as_uint(v.z), uw = __float_as_uint(v.w);
  unsigned h01 = (ux >> 16) | (uy & 0xFFFF0000u);
  unsigned h23 = (uz >> 16) | (uw & 0xFFFF0000u);
  float lx = v.x - __uint_as_float(ux & 0xFFFF0000u);
  float ly = v.y - __uint_as_float(uy & 0xFFFF0000u);
  float lz = v.z - __uint_as_float(uz & 0xFFFF0000u);
  float lw = v.w - __uint_as_float(uw & 0xFFFF0000u);
  unsigned l01 = ph(lx, ly);
  unsigned l23 = ph(lz, lw);
  return u2f(make_uint4(h01, h23, l01, l23));
}
__device__ __forceinline__ f32x4 MF(bf16x8 a, bf16x8 b, f32x4 c) {
  return __builtin_amdgcn_mfma_f32_16x16x32_bf16(a, b, c, 0, 0, 0);
}

// ---------------- kernel 1: Cholesky / softmax params ----------------
__global__ __launch_bounds__(64) void prep_kernel(
    const float* __restrict__ pi, const float* __restrict__ Q,
    const float* __restrict__ init_cov, const float* __restrict__ covs,
    float* __restrict__ prm)
{
  int tid = threadIdx.x;
  int blk = blockIdx.x;
  if (blk < 16) {
    int k = blk & 7;
    const float* C = (blk < 8 ? init_cov : covs) + k*256;
    float* outL  = prm + (blk < 8 ? P_LINV0 : P_LINVT) + k*256;
    float* outld = prm + (blk < 8 ? P_LD0   : P_LDT)   + k;
    __shared__ float S[16][17], L[16][17], X[16][17];
    for (int e = tid; e < 256; e += 64) {
      int r = e >> 4, c = e & 15;
      float s = (r == c) ? 1e-6f : 0.f;
      for (int l = 0; l < 16; l++) s += C[r*16+l] * C[c*16+l];
      S[r][c] = s;
    }
    __syncthreads();
    for (int j = 0; j < 16; j++) {
      if (tid == 0) L[j][j] = sqrtf(S[j][j]);
      __syncthreads();
      if (tid > j && tid < 16) L[tid][j] = S[tid][j] / L[j][j];
      __syncthreads();
      if (tid > j && tid < 16) {
        float ltj = L[tid][j];
        for (int c = j+1; c <= tid; c++) S[tid][c] -= ltj * L[c][j];
      }
      __syncthreads();
    }
    if (tid < 16) {
      int c = tid;
      for (int r = 0; r < 16; r++) {
        float v;
        if (r < c) v = 0.f;
        else {
          v = (r == c) ? 1.f : 0.f;
          for (int s2 = c; s2 < r; s2++) v -= L[r][s2] * X[s2][c];
          v /= L[r][r];
        }
        X[r][c] = v;
      }
    }
    __syncthreads();
    for (int e = tid; e < 256; e += 64) outL[e] = X[e>>4][e&15];
    if (tid == 0) {
      float ld = 0.f;
      for (int j = 0; j < 16; j++) ld += logf(L[j][j]);
      *outld = ld;
    }
  } else {
    if (tid < 8) {
      int row = tid;
      float q[8], mx = -1e30f;
      for (int j = 0; j < 8; j++) { q[j] = Q[row*8+j]; mx = fmaxf(mx, q[j]); }
      float s = 0.f;
      for (int j = 0; j < 8; j++) s += __expf(q[j]-mx);
      float ls = logf(s);
      for (int j = 0; j < 8; j++) {
        float e = __expf(q[j]-mx-ls);
        prm[P_QEXP  + row*8 + j] = e;
        prm[P_QTEXP + j*8 + row] = e;
      }
    } else if (tid == 8) {
      float p[8], mx = -1e30f;
      for (int j = 0; j < 8; j++) { p[j] = pi[j]; mx = fmaxf(mx, p[j]); }
      float s = 0.f;
      for (int j = 0; j < 8; j++) s += __expf(p[j]-mx);
      float ls = logf(s);
      for (int j = 0; j < 8; j++) prm[P_LOGPI+j] = p[j]-mx-ls;
    }
  }
}

// ---------------- kernel 1c: pack MFMA frag params ----------------
__global__ __launch_bounds__(64) void prep2_kernel(
    const float* __restrict__ W1, const float* __restrict__ W2,
    const float* __restrict__ b2, const float* __restrict__ init_mean,
    const float* __restrict__ prm, float* __restrict__ frag)
{
  int k = blockIdx.x, tid = threadIdx.x;
  __shared__ float Ls[16][16], L0s[16][16], G[16][64];
  for (int e = tid; e < 256; e += 64) {
    Ls[e>>4][e&15]  = prm[P_LINVT + k*256 + e];
    L0s[e>>4][e&15] = prm[P_LINV0 + k*256 + e];
  }
  __syncthreads();
  for (int idx = tid; idx < 1024; idx += 64) {
    int d = idx >> 6, hh = idx & 63;
    float s = 0.f;
    for (int e = 0; e < 16; e++) s += Ls[d][e] * W2[k*1024 + e*64 + hh];
    G[d][hh] = -s;
  }
  __syncthreads();
  int d = tid & 15, q = tid >> 4;
  uint4* F4 = (uint4*)frag;
  for (int kc = 0; kc < 2; kc++) {
    float v[8], lo[8];
    for (int j = 0; j < 8; j++) {
      int hh = 32*kc + 16*(j>>2) + 4*q + (j&3);
      v[j] = G[d][hh];
      lo[j] = v[j] - hif(v[j]);
    }
    F4[6144 + ((k*2+kc)*4+q)*16 + d] =
        make_uint4(ph(v[0],v[1]), ph(v[2],v[3]), ph(v[4],v[5]), ph(v[6],v[7]));
    F4[7168 + ((k*2+kc)*4+q)*16 + d] =
        make_uint4(ph(lo[0],lo[1]), ph(lo[2],lo[3]), ph(lo[4],lo[5]), ph(lo[6],lo[7]));
  }
  for (int mt = 0; mt < 4; mt++) {
    int hh = 16*mt + d;
    float v[4], lo[4];
    for (int j = 0; j < 4; j++) { v[j] = W1[k*1024 + hh*16 + 4*q + j]; lo[j] = v[j] - hif(v[j]); }
    unsigned x = ph(v[0],v[1]), y = ph(v[2],v[3]);
    F4[((k*4+mt)*4+q)*16 + d]        = make_uint4(x, y, x, y);
    F4[2048 + ((k*4+mt)*4+q)*16 + d] = make_uint4(ph(lo[0],lo[1]), ph(lo[2],lo[3]), 0u, 0u);
  }
  {
    float v[4], lo[4];
    for (int j = 0; j < 4; j++) { v[j] = Ls[d][4*q+j]; lo[j] = v[j] - hif(v[j]); }
    unsigned x = ph(v[0],v[1]), y = ph(v[2],v[3]);
    F4[4096 + (k*4+q)*16 + d] = make_uint4(x, y, x, y);
    F4[4608 + (k*4+q)*16 + d] = make_uint4(ph(lo[0],lo[1]), ph(lo[2],lo[3]), 0u, 0u);
    for (int j = 0; j < 4; j++) { v[j] = L0s[d][4*q+j]; lo[j] = v[j] - hif(v[j]); }
    x = ph(v[0],v[1]); y = ph(v[2],v[3]);
    F4[5120 + (k*4+q)*16 + d] = make_uint4(x, y, x, y);
    F4[5632 + (k*4+q)*16 + d] = make_uint4(ph(lo[0],lo[1]), ph(lo[2],lo[3]), 0u, 0u);
  }
  if (q == 0) {
    float s2 = 0.f, s0 = 0.f;
    for (int e = 0; e < 16; e++) {
      s2 += Ls[d][e]  * b2[k*16+e];
      s0 += L0s[d][e] * init_mean[k*16+e];
    }
    frag[FI_NC2 + k*16 + d] = -s2;
    frag[FI_C0I + k*16 + d] = -s0;
  }
}

// ---------------- kernel 1b: z -> time-major zT[t][b][16] --------------------
__global__ __launch_bounds__(256) void ztr_kernel(
    const float* __restrict__ z, float* __restrict__ zt)
{
  int tid = blockIdx.x*256 + threadIdx.x;
  int t = tid >> 6, b = tid & 63;
  const float4* src = (const float4*)(z + (b*T_ + t)*LD_);
  float4* dst = (float4*)(zt + t*1024 + b*16);
  dst[0] = src[0]; dst[1] = src[1]; dst[2] = src[2]; dst[3] = src[3];
}

// ---------------- kernel 2: emissions via MFMA (split-bf16 ~fp32) ------------
// 8 t-steps per wave (2048 blocks) for occupancy.
__global__ __launch_bounds__(256) void emisB_kernel(
    const float* __restrict__ zt, const float* __restrict__ b1,
    const float* __restrict__ frag, const float* __restrict__ prm,
    float* __restrict__ lebuf)
{
  int lane = threadIdx.x & 63;
  int wid = __builtin_amdgcn_readfirstlane(blockIdx.x*4 + (threadIdx.x >> 6));
  int bblk = wid & 3;
  int tch  = (wid >> 2) & 255;
  int k    = wid >> 10;
  int c = lane & 15, q = lane >> 4;
  int b = bblk*16 + c;
  const uint4* F4 = (const uint4*)frag;

  bf16x8 w1a1[4], w1a2[4];
  #pragma unroll
  for (int mt = 0; mt < 4; mt++) {
    w1a1[mt] = u2f(F4[((k*4+mt)*4+q)*16 + c]);
    w1a2[mt] = u2f(F4[2048 + ((k*4+mt)*4+q)*16 + c]);
  }
  bf16x8 lva1 = u2f(F4[4096 + (k*4+q)*16 + c]);
  bf16x8 lva2 = u2f(F4[4608 + (k*4+q)*16 + c]);
  bf16x8 gahi[2], galo[2];
  #pragma unroll
  for (int kc = 0; kc < 2; kc++) {
    gahi[kc] = u2f(F4[6144 + ((k*2+kc)*4+q)*16 + c]);
    galo[kc] = u2f(F4[7168 + ((k*2+kc)*4+q)*16 + c]);
  }
  float b1iv[16];
  #pragma unroll
  for (int i = 0; i < 16; i++)
    b1iv[i] = b1[k*64 + (i>>2)*16 + 4*q + (i&3)];
  float nc2[4];
  #pragma unroll
  for (int r = 0; r < 4; r++) nc2[r] = frag[FI_NC2 + k*16 + 4*q + r];
  float lconst = -prm[P_LDT + k] - 14.70301653f;

  int t0 = tch*8;
  bf16x8 zp;
  int ttstart;
  if (tch == 0) {
    float4 zv0 = *(const float4*)(zt + b*16 + 4*q);
    bf16x8 zc0 = mkfrag(zv0);
    bf16x8 l0a1 = u2f(F4[5120 + (k*4+q)*16 + c]);
    bf16x8 l0a2 = u2f(F4[5632 + (k*4+q)*16 + c]);
    f32x4 acc;
    acc[0] = frag[FI_C0I + k*16 + 4*q + 0];
    acc[1] = frag[FI_C0I + k*16 + 4*q + 1];
    acc[2] = frag[FI_C0I + k*16 + 4*q + 2];
    acc[3] = frag[FI_C0I + k*16 + 4*q + 3];
    acc = MF(l0a1, zc0, acc);
    acc = MF(l0a2, zc0, acc);
    float m2 = (acc[0]*acc[0] + acc[1]*acc[1]) + (acc[2]*acc[2] + acc[3]*acc[3]);
    m2 += __shfl_xor(m2, 16);
    m2 += __shfl_xor(m2, 32);
    float le = -0.5f*m2 - prm[P_LD0+k] - 14.70301653f + prm[P_LOGPI+k];
    if (q == 0) lebuf[k*64 + b] = le;
    zp = zc0;
    ttstart = 1;
  } else {
    float4 zvp = *(const float4*)(zt + (t0-1)*1024 + b*16 + 4*q);
    zp = mkfrag(zvp);
    ttstart = 0;
  }

  float4 zv = *(const float4*)(zt + (t0+ttstart)*1024 + b*16 + 4*q);
  #pragma unroll 1
  for (int tt = ttstart; tt < 8; tt++) {
    int t = t0 + tt;
    float4 zvn = zv;
    if (tt < 7) zvn = *(const float4*)(zt + (t+1)*1024 + b*16 + 4*q);
    bf16x8 zc = mkfrag(zv);
    f32x4 a1[4];
    #pragma unroll
    for (int mt = 0; mt < 4; mt++) {
      f32x4 ai;
      ai[0] = b1iv[mt*4+0]; ai[1] = b1iv[mt*4+1];
      ai[2] = b1iv[mt*4+2]; ai[3] = b1iv[mt*4+3];
      ai = MF(w1a1[mt], zp, ai);
      a1[mt] = MF(w1a2[mt], zp, ai);
    }
    float hv[16];
    #pragma unroll
    for (int i = 0; i < 16; i++) {
      float a = a1[i>>2][i&3];
      hv[i] = fmaxf(a, 0.f) + __logf(1.f + __expf(-fabsf(a)));
    }
    bf16x8 hhi[2], hlo[2];
    #pragma unroll
    for (int kc = 0; kc < 2; kc++) {
      const float* hp = hv + 8*kc;
      hhi[kc] = u2f(make_uint4(ph(hp[0],hp[1]), ph(hp[2],hp[3]),
                               ph(hp[4],hp[5]), ph(hp[6],hp[7])));
      float l0 = hp[0]-hif(hp[0]), l1 = hp[1]-hif(hp[1]);
      float l2 = hp[2]-hif(hp[2]), l3 = hp[3]-hif(hp[3]);
      float l4 = hp[4]-hif(hp[4]), l5 = hp[5]-hif(hp[5]);
      float l6 = hp[6]-hif(hp[6]), l7 = hp[7]-hif(hp[7]);
      hlo[kc] = u2f(make_uint4(ph(l0,l1), ph(l2,l3), ph(l4,l5), ph(l6,l7)));
    }
    f32x4 acc;
    acc[0] = nc2[0]; acc[1] = nc2[1]; acc[2] = nc2[2]; acc[3] = nc2[3];
    acc = MF(lva1, zc, acc);
    acc = MF(lva2, zc, acc);
    #pragma unroll
    for (int kc = 0; kc < 2; kc++) {
      acc = MF(gahi[kc], hhi[kc], acc);
      acc = MF(galo[kc], hhi[kc], acc);
      acc = MF(gahi[kc], hlo[kc], acc);
    }
    float m2 = (acc[0]*acc[0] + acc[1]*acc[1]) + (acc[2]*acc[2] + acc[3]*acc[3]);
    m2 += __shfl_xor(m2, 16);
    m2 += __shfl_xor(m2, 32);
    float le = -0.5f*m2 + lconst;
    if (q == 0) lebuf[t*512 + k*64 + b] = le;
    zp = zc;
    zv = zvn;
  }
}

// ---------------- fwdA: P1 chunk products + in-wave super product (P2a) ------
// unit = (b,s) = one 64-lane wave: 8 groups x 8 lanes; group u <-> chunk 8s+u
__global__ __launch_bounds__(256) void fwdA_kernel(
    const float* __restrict__ lebuf, const float* __restrict__ prm,
    float* __restrict__ pbuf, float* __restrict__ sbuf)
{
  int lane64 = threadIdx.x & 63;
  int iu = threadIdx.x >> 6;
  int unit = blockIdx.x*4 + iu;       // 0..1023
  int b = unit & 63, s = unit >> 6;
  int u = lane64 >> 3, j = lane64 & 7;
  int c = 8*s + u;
  // ---- P1: chunk operator product ----
  float qtv[64];
  #pragma unroll
  for (int x = 0; x < 8; x++)
    #pragma unroll
    for (int v = 0; v < 8; v++)
      qtv[x*8+v] = prm[P_QTEXP + (j^x)*8 + (j^v)];
  float lev[16];
  #pragma unroll
  for (int x = 0; x < 16; x++) lev[x] = lebuf[(c*L_+x)*512 + j*64 + b];
  float pl[8];
  if (c == 0) {
    float m = bfly_max8(lev[0]);
    float e = __expf(lev[0]-m);
    allg8(e, pl);                 // P[:,j] = ehat_0
  } else {
    // step 0 with pl = identity column 0: np[x] = e8[x] * qtv[x*8+0]
    float m = bfly_max8(lev[0]);
    float e = __expf(lev[0]-m);
    float e8[8]; allg8(e, e8);
    float np[8];
    #pragma unroll
    for (int x = 0; x < 8; x++) np[x] = e8[x] * qtv[x*8];
    float mx = np[0];
    #pragma unroll
    for (int x = 1; x < 8; x++) mx = fmaxf(mx, np[x]);
    mx = bfly_max8(mx);
    float r = rcpnr(mx);
    #pragma unroll
    for (int x = 0; x < 8; x++) pl[x] = np[x] * r;
  }
  #pragma unroll
  for (int sx = 1; sx < 16; sx++) {
    float m = bfly_max8(lev[sx]);
    float e = __expf(lev[sx]-m);
    float e8[8]; allg8(e, e8);
    float np[8];
    #pragma unroll
    for (int x = 0; x < 8; x++) {
      float acc = 0.f;
      #pragma unroll
      for (int v = 0; v < 8; v++) acc = __builtin_fmaf(qtv[x*8+v], pl[v], acc);
      np[x] = e8[x] * acc;
    }
    float mx = np[0];
    #pragma unroll
    for (int x = 1; x < 8; x++) mx = fmaxf(mx, np[x]);
    mx = bfly_max8(mx);
    float r = rcpnr(mx);
    #pragma unroll
    for (int x = 0; x < 8; x++) pl[x] = np[x] * r;
  }
  float rv[8]; col2row(pl, rv);
  float4* dst = (float4*)(pbuf + (c*64 + b)*64 + j*8);
  dst[0] = make_float4(rv[0], rv[1], rv[2], rv[3]);
  dst[1] = make_float4(rv[4], rv[5], rv[6], rv[7]);
  // ---- P2a: serial in-block super product S_s = P7*...*P0 ----
  __shared__ float M[4][8][64];
  #pragma unroll
  for (int v = 0; v < 8; v++) M[iu][u][j*8+v] = rv[v];
  __syncthreads();
  if (u == 0) {
    float m[8];
    #pragma unroll
    for (int v = 0; v < 8; v++) m[v] = M[iu][0][j*8+v];
    for (int cc = 1; cc < 8; cc++) {
      float a[8];
      #pragma unroll
      for (int v = 0; v < 8; v++) a[v] = M[iu][cc][j*8+v];
      float nm[8];
      mmul8(a, m, nm);
      maxnorm8(nm);
      #pragma unroll
      for (int v = 0; v < 8; v++) m[v] = nm[v];
    }
    float4* d2 = (float4*)(sbuf + (s*64 + b)*64 + j*8);
    d2[0] = make_float4(m[0], m[1], m[2], m[3]);
    d2[1] = make_float4(m[4], m[5], m[6], m[7]);
  }
}

// ---------------- fwd P2b: serial over 16 supers -> sain ---------------------
__global__ __launch_bounds__(512) void fwdP2b_kernel(
    const float* __restrict__ sbuf, float* __restrict__ sain)
{
  int lane = threadIdx.x;
  int b = lane >> 3, i = lane & 7;
  const float4* base = (const float4*)sbuf;
  float4 c0 = base[(0*64+b)*16 + i*2], c1 = base[(0*64+b)*16 + i*2 + 1];
  float a = 0.125f;
  for (int s = 0; s < 16; s++) {
    int s2 = (s < 15) ? s+1 : 15;
    float4 n0 = base[(s2*64+b)*16 + i*2], n1 = base[(s2*64+b)*16 + i*2 + 1];
    float aw[8]; allg8(a, aw);
    float sm = ((c0.x*aw[0] + c0.y*aw[1]) + (c0.z*aw[2] + c0.w*aw[3]))
             + ((c1.x*aw[4] + c1.y*aw[5]) + (c1.z*aw[6] + c1.w*aw[7]));
    float tot = bfly_sum8(sm);
    float an = sm * rcpnr(tot);
    if (s < 15) { a = an; sain[(s+1)*512 + b*8 + i] = a; }
    c0 = n0; c1 = n1;
  }
}

// ---------------- fwdB: P2c walk + P3 scan + R product + U_s (bwdP2a) --------
// unit = (b,s) = one wave; group u <-> chunk c = 8s+u
__global__ __launch_bounds__(256) void fwdB_kernel(
    const float* __restrict__ lebuf, const float* __restrict__ prm,
    const float* __restrict__ sain, float* pbuf,
    float* __restrict__ alpha, float* __restrict__ ebar,
    float* __restrict__ rlog, float* __restrict__ ubuf,
    float* __restrict__ ulog, float* __restrict__ out)
{
  int lane64 = threadIdx.x & 63;
  int iu = threadIdx.x >> 6;
  int unit = blockIdx.x*4 + iu;
  int b = unit & 63, s = unit >> 6;
  int u = lane64 >> 3, i = lane64 & 7;
  int c = 8*s + u;
  int off = b*8 + i;
  __shared__ float Als[4][8];
  __shared__ float Mh[4][8][64];
  __shared__ float Lh[4][8];
  // load own chunk's P rows (for the walk), and emissions (prefetch)
  float pr[8];
  load_rows(pbuf + (c*64 + b)*64 + i*8, pr);
  float lev[16];
  #pragma unroll
  for (int x = 0; x < 16; x++) lev[x] = lebuf[(c*L_+x)*512 + i*64 + b];
  // ---- serial walk (P2c): a-in per chunk via LDS handoff ----
  float av_in = 0.f;
  if (u == 0) av_in = (s == 0) ? 0.125f : sain[s*512 + off];
  for (int r = 0; r < 7; r++) {
    if (u == r) {
      if (r > 0) av_in = Als[iu][i];
      float aw[8]; allg8(av_in, aw);
      float sm = dotw8(pr, aw);
      float tot = bfly_sum8(sm);
      Als[iu][i] = sm * rcpnr(tot);
    }
    __syncthreads();
  }
  if (u == 7) av_in = Als[iu][i];
  // ---- P3 scan ----
  float q[8];
  #pragma unroll
  for (int x = 0; x < 8; x++) q[x] = prm[P_QTEXP + i*8 + (i^x)];
  float* logZ = out + OUT_LOGZ + b*T_;
  float eb_loc[16];
  float a;
  if (c == 0) {
    float m0 = bfly_max8(lev[0]);
    float e0x = __expf(lev[0]-m0);
    float ct = bfly_sum8(e0x);
    float rr = rcpnr(ct);
    a = e0x * rr;
    alpha[off] = a;
    eb_loc[0] = a;
    ebar[off] = a;
    if (i == 0) logZ[0] = m0 + __logf(ct);
  } else {
    a = av_in;
    int t = c*L_;
    float m = bfly_max8(lev[0]);
    float e = __expf(lev[0]-m);
    float w[8]; allg8(a, w);
    float dot = dotw8(q, w);
    float p = e * dot;
    float ct = bfly_sum8(p);
    float rr = rcpnr(ct);
    a = p * rr;
    alpha[t*512 + off] = a;
    float eb = e * rr;
    eb_loc[0] = eb;
    ebar[t*512 + off] = eb;
    if (i == 0) logZ[t] = m + __logf(ct);
  }
  #pragma unroll
  for (int x = 1; x < 16; x++) {
    int t = c*L_ + x;
    float m = bfly_max8(lev[x]);
    float e = __expf(lev[x]-m);
    float w[8]; allg8(a, w);
    float dot = dotw8(q, w);
    float p = e * dot;
    float ct = bfly_sum8(p);
    float rr = rcpnr(ct);
    a = p * rr;
    alpha[t*512 + off] = a;
    float eb = e * rr;
    eb_loc[x] = eb;
    ebar[t*512 + off] = eb;
    if (i == 0) logZ[t] = m + __logf(ct);
  }
  // ---- backward chunk product R_c = Q E_{cL+1} ... Q E_{cL+15} ----
  float qv[64];
  #pragma unroll
  for (int x = 0; x < 8; x++)
    #pragma unroll
    for (int v = 0; v < 8; v++)
      qv[x*8+v] = prm[P_QEXP + (i^x)*8 + (i^v)];
  float rl8[8];
  #pragma unroll
  for (int x = 0; x < 8; x++) rl8[x] = (x == 0) ? 1.f : 0.f;
  float lsc = 0.f;
  #pragma unroll
  for (int sx = 15; sx >= 1; sx--) {
    float e8[8]; allg8(eb_loc[sx], e8);
    float nr[8];
    #pragma unroll
    for (int x = 0; x < 8; x++) {
      float acc = 0.f;
      #pragma unroll
      for (int v = 0; v < 8; v++) acc = __builtin_fmaf(qv[x*8+v], e8[v]*rl8[v], acc);
      nr[x] = acc;
    }
    float mx = nr[0];
    #pragma unroll
    for (int x = 1; x < 8; x++) mx = fmaxf(mx, nr[x]);
    mx = bfly_max8(mx);
    float r = rcpnr(mx);
    #pragma unroll
    for (int x = 0; x < 8; x++) rl8[x] = nr[x] * r;
    lsc += __logf(mx);
  }
  float rv[8]; col2row(rl8, rv);
  float4* dstR = (float4*)(pbuf + (c*64 + b)*64 + i*8);   // R overwrites P
  dstR[0] = make_float4(rv[0], rv[1], rv[2], rv[3]);
  dstR[1] = make_float4(rv[4], rv[5], rv[6], rv[7]);
  if (i == 0) rlog[c*64 + b] = lsc;
  // ---- bwdP2a fused: H_c = Q diag(ebar_c0) R_c ; U_s = H_0 ... H_7 ----
  float qr[8];
  #pragma unroll
  for (int x = 0; x < 8; x++) qr[x] = prm[P_QEXP + i*8 + (i^x)];
  float d8[8];
  #pragma unroll
  for (int v = 0; v < 8; v++) d8[v] = eb_loc[0] * rv[v];
  float h8[8];
  mmul8(qr, d8, h8);
  float ls = lsc + __logf(maxnorm8(h8));
  #pragma unroll
  for (int v = 0; v < 8; v++) Mh[iu][u][i*8+v] = h8[v];
  if (i == 0) Lh[iu][u] = ls;
  __syncthreads();
  if (u == 0) {
    float m[8];
    #pragma unroll
    for (int v = 0; v < 8; v++) m[v] = Mh[iu][7][i*8+v];
    float lsum = Lh[iu][7];
    for (int cc = 6; cc >= 0; cc--) {
      float aa[8];
      #pragma unroll
      for (int v = 0; v < 8; v++) aa[v] = Mh[iu][cc][i*8+v];
      float t8[8];
      mmul8(aa, m, t8);
      lsum += Lh[iu][cc] + __logf(maxnorm8(t8));
      #pragma unroll
      for (int v = 0; v < 8; v++) m[v] = t8[v];
    }
    float4* d2 = (float4*)(ubuf + (s*64 + b)*64 + i*8);
    d2[0] = make_float4(m[0], m[1], m[2], m[3]);
    d2[1] = make_float4(m[4], m[5], m[6], m[7]);
    if (i == 0) ulog[s*64 + b] = lsum;
  }
}

// ---------------- bwd P2b: serial over supers -> bent (beta at super tops) ---
__global__ __launch_bounds__(512) void bwdP2b_kernel(
    const float* __restrict__ ubuf, const float* __restrict__ ulog,
    float* __restrict__ bent)
{
  int lane = threadIdx.x;
  int b = lane >> 3, i = lane & 7;
  bent[15*512 + b*8 + i] = 1.f;
  const float4* base = (const float4*)ubuf;
  float sh = 1.f, sig = 0.f;
  float4 c0 = base[(15*64+b)*16 + i*2], c1 = base[(15*64+b)*16 + i*2 + 1];
  float cu = ulog[15*64 + b];
  for (int s = 15; s >= 1; s--) {
    int s2 = (s > 1) ? s-1 : 1;
    float4 n0 = base[(s2*64+b)*16 + i*2], n1 = base[(s2*64+b)*16 + i*2 + 1];
    float nu = ulog[s2*64 + b];
    float sw[8]; allg8(sh, sw);
    float y = ((c0.x*sw[0] + c0.y*sw[1]) + (c0.z*sw[2] + c0.w*sw[3]))
            + ((c1.x*sw[4] + c1.y*sw[5]) + (c1.z*sw[6] + c1.w*sw[7]));
    float mx = bfly_max8(y);
    sh = y * rcpnr(mx);
    sig += cu + __logf(mx);
    bent[(s-1)*512 + b*8 + i] = sh * __expf(sig);
    c0 = n0; c1 = n1; cu = nu;
  }
}

// ---------------- bwdC: in-wave beta walk (bwdP2c) + gamma/paired (bwdP3) ----
// unit = (b,s) = one wave; group u <-> chunk c = 8s+u.
// Boundary paired/gamma at t = c*16-1 handled by the DOWNSTREAM chunk's group
// (which owns e0, sb locally) -> no global sb buffer.
__global__ __launch_bounds__(256) void bwdC_kernel(
    const float* __restrict__ alpha, const float* __restrict__ ebar,
    const float* __restrict__ rbuf, const float* __restrict__ rlog,
    const float* __restrict__ prm, const float* __restrict__ bent,
    float* __restrict__ out)
{
  int lane64 = threadIdx.x & 63;
  int iu = threadIdx.x >> 6;
  int unit = blockIdx.x*4 + iu;
  int b = unit & 63, s = unit >> 6;
  int u = lane64 >> 3, i = lane64 & 7;
  int c = 8*s + u;
  int off = b*8 + i;
  float qr[8], qa[8];
  #pragma unroll
  for (int x = 0; x < 8; x++) qr[x] = prm[P_QEXP + i*8 + (i^x)];
  #pragma unroll
  for (int v = 0; v < 8; v++) qa[v] = prm[P_QEXP + i*8 + v];
  float r8[8];
  load_rows(rbuf + (c*64 + b)*64 + i*8, r8);
  float e0 = ebar[(c*L_)*512 + off];
  float erl = __expf(rlog[c*64 + b]);
  // prefetch emission inputs (hide latency under serialized walk)
  float av[16], ev[16];
  #pragma unroll
  for (int x = 0; x < 16; x++) av[x] = alpha[(c*L_+x)*512 + off];
  #pragma unroll
  for (int x = 1; x < 16; x++) ev[x] = ebar[(c*L_+x)*512 + off];
  float avm1 = (c > 0) ? alpha[(c*L_-1)*512 + off] : 0.f;
  // ---- serial beta walk, top chunk (u=7) down to u=0 ----
  __shared__ float Bls[4][8];
  float bt = 0.f, y = 0.f, nbv = 0.f;
  for (int r = 7; r >= 0; r--) {
    if (u == r) {
      bt = (r == 7) ? bent[s*512 + off] : Bls[iu][i];
      float bw[8]; allg8(bt, bw);
      y = dotw8(r8, bw) * erl;            // beta at t = c*16 (own sb)
      float ey = e0 * y;
      float w[8]; allg8(ey, w);
      nbv = 0.f;
      #pragma unroll
      for (int v = 0; v < 8; v++) nbv = __builtin_fmaf(qr[v], w[v], nbv);
      if (r > 0) Bls[iu][i] = nbv;        // beta at t = c*16-1 -> next group
    }
    __syncthreads();
  }
  // ---- emission: gamma + paired ----
  float* po = out + OUT_PAIRED + b*((T_-1)*64);
  float* go = out + b*(T_*K_);
  float bb = bt;                          // beta at top of own chunk
  if (c == 127) go[2047*8 + i] = av[15];  // gamma at t=2047 (beta=1)
  #pragma unroll
  for (int x = 15; x >= 1; x--) {
    float eya[8]; absg8(ev[x]*bb, eya);
    float term[8];
    #pragma unroll
    for (int v = 0; v < 8; v++) term[v] = qa[v]*eya[v];
    float nb = ((term[0]+term[1]) + (term[2]+term[3]))
             + ((term[4]+term[5]) + (term[6]+term[7]));
    int t = c*L_ + x - 1;
    float am = av[x-1];
    float4* pd = (float4*)(po + t*64 + i*8);
    pd[0] = make_float4(am*term[0], am*term[1], am*term[2], am*term[3]);
    pd[1] = make_float4(am*term[4], am*term[5], am*term[6], am*term[7]);
    go[t*8 + i] = am*nb;
    bb = nb;
  }
  if (c > 0) {
    // boundary t = c*16-1 (belongs to chunk c-1's range): uses own e0, y
    float eya[8]; absg8(e0*y, eya);
    int t = c*L_ - 1;
    float4* pd = (float4*)(po + t*64 + i*8);
    pd[0] = make_float4(avm1*qa[0]*eya[0], avm1*qa[1]*eya[1],
                        avm1*qa[2]*eya[2], avm1*qa[3]*eya[3]);
    pd[1] = make_float4(avm1*qa[4]*eya[4], avm1*qa[5]*eya[5],
                        avm1*qa[6]*eya[6], avm1*qa[7]*eya[7]);
    go[t*8 + i] = avm1 * nbv;
  }
}

extern "C" void kernel_launch(void* const* d_in, const int* in_sizes, int n_in,
                              void* d_out, int out_size, void* d_ws, size_t ws_size,
                              hipStream_t stream) {
  const float* z         = (const float*)d_in[0];
  const float* pi        = (const float*)d_in[1];
  const float* Q         = (const float*)d_in[2];
  const float* init_mean = (const float*)d_in[3];
  const float* init_cov  = (const float*)d_in[4];
  const float* covs      = (const float*)d_in[5];
  const float* W1        = (const float*)d_in[6];
  const float* b1        = (const float*)d_in[7];
  const float* W2        = (const float*)d_in[8];
  const float* b2        = (const float*)d_in[9];
  float* out = (float*)d_out;
  float* ws  = (float*)d_ws;

  prep_kernel<<<17, 64, 0, stream>>>(pi, Q, init_cov, covs, ws + OFF_PRM);
  prep2_kernel<<<8, 64, 0, stream>>>(W1, W2, b2, init_mean, ws + OFF_PRM,
                                     ws + OFF_UBUF);
  ztr_kernel<<<512, 256, 0, stream>>>(z, ws + OFF_ZT);
  emisB_kernel<<<2048, 256, 0, stream>>>(ws + OFF_ZT, b1, ws + OFF_UBUF,
                                         ws + OFF_PRM, ws + OFF_LE);
  fwdA_kernel<<<256, 256, 0, stream>>>(ws + OFF_LE, ws + OFF_PRM,
                                       ws + OFF_PBUF, ws + OFF_SBUF);
  fwdP2b_kernel<<<1, 512, 0, stream>>>(ws + OFF_SBUF, ws + OFF_SAIN);
  fwdB_kernel<<<256, 256, 0, stream>>>(ws + OFF_LE, ws + OFF_PRM, ws + OFF_SAIN,
                                       ws + OFF_PBUF, ws + OFF_ALPHA,
                                       ws + OFF_EBAR, ws + OFF_RLOG,
                                       ws + OFF_UBUF, ws + OFF_ULOG, out);
  bwdP2b_kernel<<<1, 512, 0, stream>>>(ws + OFF_UBUF, ws + OFF_ULOG, ws + OFF_BENT);
  bwdC_kernel<<<256, 256, 0, stream>>>(ws + OFF_ALPHA, ws + OFF_EBAR,
                                       ws + OFF_PBUF, ws + OFF_RLOG,
                                       ws + OFF_PRM, ws + OFF_BENT, out);
}